// Round 1
// baseline (60.038 us; speedup 1.0000x reference)
//
#include <hip/hip_runtime.h>

#define C_CH 128
#define H_IN 80
#define W_IN 80
#define HW 6400
#define NBINS 49   // 7x7

// ---------------- transpose (B,C,H,W) -> (B,H,W,C) ----------------
__global__ __launch_bounds__(256) void transpose_kernel(const float* __restrict__ in,
                                                        float* __restrict__ out) {
    __shared__ float tile[32][33];
    const int b  = blockIdx.z;
    const int c0 = blockIdx.y * 32;   // channel tile
    const int s0 = blockIdx.x * 32;   // spatial (h*W+w) tile
    const int tx = threadIdx.x, ty = threadIdx.y;  // block (32,8)
#pragma unroll
    for (int i = 0; i < 32; i += 8)
        tile[ty + i][tx] = in[(size_t)(b * C_CH + c0 + ty + i) * HW + s0 + tx];
    __syncthreads();
#pragma unroll
    for (int i = 0; i < 32; i += 8)
        out[(size_t)(b * HW + s0 + ty + i) * C_CH + c0 + tx] = tile[tx][ty + i];
}

// ---------------- main deformable RoI pool ----------------
// One block (512 threads = 8 waves) per roi. Wave w handles bins w, w+8, ...
// Lane l covers channels l and l+64. Results staged in LDS [c][bin] (stride 49
// is odd -> conflict-free), then written flat-coalesced to out[n, c, ph, pw].
template <bool TRANSPOSED>
__global__ __launch_bounds__(512) void droi_kernel(const float* __restrict__ data,
                                                   const float* __restrict__ rois,
                                                   const float* __restrict__ offset,
                                                   float* __restrict__ out) {
#pragma clang fp contract(off)
    __shared__ float lds[C_CH * NBINS];
    const int n    = blockIdx.x;
    const int tid  = threadIdx.x;
    const int wave = tid >> 6;
    const int lane = tid & 63;

    const int   b     = (int)rois[n * 5 + 0];
    const float sw    = rintf(rois[n * 5 + 1]) * 0.0625f - 0.5f;
    const float sh    = rintf(rois[n * 5 + 2]) * 0.0625f - 0.5f;
    const float ew    = (rintf(rois[n * 5 + 3]) + 1.0f) * 0.0625f - 0.5f;
    const float eh    = (rintf(rois[n * 5 + 4]) + 1.0f) * 0.0625f - 0.5f;
    const float roi_w = fmaxf(ew - sw, 0.1f);
    const float roi_h = fmaxf(eh - sh, 0.1f);
    const float bin_w = roi_w / 7.0f;
    const float bin_h = roi_h / 7.0f;
    const float sub_w = bin_w / 4.0f;
    const float sub_h = bin_h / 4.0f;

    for (int bin = wave; bin < NBINS; bin += 8) {
        const int ph = bin / 7;
        const int pw = bin - ph * 7;
        // PART_SIZE == OUT_SIZE == 7 -> part_h == ph, part_w == pw (verified
        // floor(ph/7*7)==ph for ph in 0..6 in f32).
        const float tx = offset[((n * 2 + 0) * 7 + ph) * 7 + pw] * 0.1f;
        const float ty = offset[((n * 2 + 1) * 7 + ph) * 7 + pw] * 0.1f;
        const float wstart = (float)pw * bin_w + sw + tx * roi_w;
        const float hstart = (float)ph * bin_h + sh + ty * roi_h;

        float s0 = 0.0f, s1 = 0.0f;
        int   cnt = 0;
        for (int ih = 0; ih < 4; ih++) {
            const float h = hstart + (float)ih * sub_h;
            if (h < -0.5f || h > (float)H_IN - 0.5f) continue;  // wave-uniform
            for (int iw = 0; iw < 4; iw++) {
                const float w = wstart + (float)iw * sub_w;
                if (w < -0.5f || w > (float)W_IN - 0.5f) continue;
                cnt++;
                const float hc = fminf(fmaxf(h, 0.0f), (float)H_IN - 1.0f);
                const float wc = fminf(fmaxf(w, 0.0f), (float)W_IN - 1.0f);
                const int h0 = (int)floorf(hc), w0 = (int)floorf(wc);
                const int h1 = min(h0 + 1, H_IN - 1), w1 = min(w0 + 1, W_IN - 1);
                const float lh = hc - (float)h0, lw = wc - (float)w0;
                const float w00 = (1.0f - lh) * (1.0f - lw);
                const float w01 = (1.0f - lh) * lw;
                const float w10 = lh * (1.0f - lw);
                const float w11 = lh * lw;
                if (TRANSPOSED) {
                    const float* p00 = data + ((size_t)(b * HW + h0 * W_IN + w0) << 7);
                    const float* p01 = data + ((size_t)(b * HW + h0 * W_IN + w1) << 7);
                    const float* p10 = data + ((size_t)(b * HW + h1 * W_IN + w0) << 7);
                    const float* p11 = data + ((size_t)(b * HW + h1 * W_IN + w1) << 7);
                    s0 += w00 * p00[lane] + w01 * p01[lane] + w10 * p10[lane] + w11 * p11[lane];
                    s1 += w00 * p00[lane + 64] + w01 * p01[lane + 64] +
                          w10 * p10[lane + 64] + w11 * p11[lane + 64];
                } else {
                    const float* pb  = data + (size_t)b * C_CH * HW;
                    const int i00 = h0 * W_IN + w0, i01 = h0 * W_IN + w1;
                    const int i10 = h1 * W_IN + w0, i11 = h1 * W_IN + w1;
                    const float* pc0 = pb + (size_t)lane * HW;
                    const float* pc1 = pb + (size_t)(lane + 64) * HW;
                    s0 += w00 * pc0[i00] + w01 * pc0[i01] + w10 * pc0[i10] + w11 * pc0[i11];
                    s1 += w00 * pc1[i00] + w01 * pc1[i01] + w10 * pc1[i10] + w11 * pc1[i11];
                }
            }
        }
        const float o0 = cnt > 0 ? s0 / (float)cnt : 0.0f;
        const float o1 = cnt > 0 ? s1 / (float)cnt : 0.0f;
        lds[lane * NBINS + bin]        = o0;
        lds[(lane + 64) * NBINS + bin] = o1;
    }
    __syncthreads();
    const size_t obase = (size_t)n * (C_CH * NBINS);
    for (int f = tid; f < C_CH * NBINS; f += 512)
        out[obase + f] = lds[f];
}

extern "C" void kernel_launch(void* const* d_in, const int* in_sizes, int n_in,
                              void* d_out, int out_size, void* d_ws, size_t ws_size,
                              hipStream_t stream) {
    const float* data   = (const float*)d_in[0];
    const float* rois   = (const float*)d_in[1];
    const float* offset = (const float*)d_in[2];
    float*       outp   = (float*)d_out;

    const int N = in_sizes[1] / 5;                 // 512
    const int B = in_sizes[0] / (C_CH * HW);       // 2
    const size_t need = (size_t)B * HW * C_CH * sizeof(float);

    if (ws_size >= need) {
        dim3 gt(HW / 32, C_CH / 32, B), bt(32, 8);
        transpose_kernel<<<gt, bt, 0, stream>>>(data, (float*)d_ws);
        droi_kernel<true><<<N, 512, 0, stream>>>((const float*)d_ws, rois, offset, outp);
    } else {
        droi_kernel<false><<<N, 512, 0, stream>>>(data, rois, offset, outp);
    }
}